// Round 4
// baseline (5013.489 us; speedup 1.0000x reference)
//
#include <hip/hip_runtime.h>

// Sinkhorn-Knopp, linear domain, ONE kernel (one pass over P) per iteration.
//   P = exp((mean+std*eps)/TAU), bf16 in ws (f32-in-d_out fallback).
//   iter t: v_j = rcp(csum_prev[j]) on the fly;
//           u_i = rcp(sum_j P_ij v_j)        (block owns 8 rows -> local reduce)
//           atomicAdd(csum_cur[j], sum_i u_i P_ij)   (thread owns 8 cols)
//   Cross-iteration sync = kernel launch boundary (implicit agent-scope acq/rel;
//   hand-rolled grid barriers measured ~70us/barrier on 8 XCDs in R3 - avoid).
//   csum triple-buffered: read prev / atomic-write cur / reset the stale third.

constexpr int N    = 4096;
constexpr int IT   = 30;
constexpr int NBLK = 512;           // iter kernel blocks; 8 rows per block
constexpr int TPB  = 512;           // 8 waves; thread owns 8 cols

typedef __attribute__((ext_vector_type(8))) unsigned short ushort8v;

__device__ inline float bf2f(unsigned int h) {
    union { unsigned int u; float f; } x; x.u = h << 16; return x.f;
}
__device__ inline unsigned short f2bf(float f) {
    union { float f; unsigned int u; } x; x.f = f;
    unsigned int r = x.u + 0x7FFFu + ((x.u >> 16) & 1u);   // round-nearest-even
    return (unsigned short)(r >> 16);
}

struct V8 { float v[8]; };

template<typename PT>
__device__ inline V8 loadP8(const PT* base, int e);
template<> __device__ inline V8 loadP8<unsigned short>(const unsigned short* base, int e) {
    ushort8v p = *(const ushort8v*)(base + e);             // one dwordx4
    V8 r;
    #pragma unroll
    for (int k = 0; k < 8; ++k) r.v[k] = bf2f((unsigned int)p[k]);
    return r;
}
template<> __device__ inline V8 loadP8<float>(const float* base, int e) {
    float4 a = *(const float4*)(base + e);
    float4 b = *(const float4*)(base + e + 4);
    V8 r = {{a.x, a.y, a.z, a.w, b.x, b.y, b.z, b.w}};
    return r;
}

// ---------------------------------------------------------------- init ------
// One chunk of 8 elements per thread (one-shot, max MLP: 6 loads in flight).
template<typename PT>
__global__ __launch_bounds__(512) void k_init(const float* __restrict__ eps,
                                              const float* __restrict__ mean,
                                              const float* __restrict__ stdv,
                                              PT* __restrict__ P,
                                              float* __restrict__ buf0,
                                              float* __restrict__ buf1) {
    const int idx = blockIdx.x * 512 + threadIdx.x;        // 0 .. N*N/8-1
    const float4* e4 = (const float4*)eps;
    const float4* m4 = (const float4*)mean;
    const float4* s4 = (const float4*)stdv;
    float4 e0 = e4[2 * (size_t)idx], e1 = e4[2 * (size_t)idx + 1];
    float4 m0 = m4[2 * (size_t)idx], m1 = m4[2 * (size_t)idx + 1];
    float4 s0 = s4[2 * (size_t)idx], s1 = s4[2 * (size_t)idx + 1];
    float p[8];
    p[0] = __expf((m0.x + s0.x * e0.x) * 0.5f);
    p[1] = __expf((m0.y + s0.y * e0.y) * 0.5f);
    p[2] = __expf((m0.z + s0.z * e0.z) * 0.5f);
    p[3] = __expf((m0.w + s0.w * e0.w) * 0.5f);
    p[4] = __expf((m1.x + s1.x * e1.x) * 0.5f);
    p[5] = __expf((m1.y + s1.y * e1.y) * 0.5f);
    p[6] = __expf((m1.z + s1.z * e1.z) * 0.5f);
    p[7] = __expf((m1.w + s1.w * e1.w) * 0.5f);
    if constexpr (sizeof(PT) == 2) {
        ushort8v o;
        #pragma unroll
        for (int k = 0; k < 8; ++k) o[k] = f2bf(p[k]);
        *(ushort8v*)((unsigned short*)P + 8 * (size_t)idx) = o;
    } else {
        float4* o4 = (float4*)P;
        float4 a = {p[0], p[1], p[2], p[3]}, b = {p[4], p[5], p[6], p[7]};
        o4[2 * (size_t)idx]     = a;
        o4[2 * (size_t)idx + 1] = b;
    }
    if (idx < N) { buf0[idx] = 1.0f; buf1[idx] = 0.0f; }   // v_0 = 1; cur_1 = 0
}

// ------------------------------------------------------- fused iteration ----
// Block b: rows [8b, 8b+8). Thread t: cols [8t, 8t+8). One pass over the tile.
template<typename PT>
__global__ __launch_bounds__(TPB) void k_iter(const PT* __restrict__ P,
                                              const float* __restrict__ csum_prev,
                                              float* __restrict__ csum_cur,
                                              float* __restrict__ csum_reset,
                                              float* __restrict__ u_glob) {
    __shared__ float ldsRow[8][8];   // [row][wave]
    __shared__ float ldsU[8];
    const int t    = threadIdx.x;
    const int wv   = t >> 6, lane = t & 63;
    const int b    = blockIdx.x;
    const int col0 = t * 8;
    const int row0 = b * 8;

    // v for my 8 cols (csum_prev written last dispatch -> coherent via boundary)
    float4 c0 = *(const float4*)&csum_prev[col0];
    float4 c1 = *(const float4*)&csum_prev[col0 + 4];
    float v[8];
    v[0] = __builtin_amdgcn_rcpf(c0.x);  v[1] = __builtin_amdgcn_rcpf(c0.y);
    v[2] = __builtin_amdgcn_rcpf(c0.z);  v[3] = __builtin_amdgcn_rcpf(c0.w);
    v[4] = __builtin_amdgcn_rcpf(c1.x);  v[5] = __builtin_amdgcn_rcpf(c1.y);
    v[6] = __builtin_amdgcn_rcpf(c1.z);  v[7] = __builtin_amdgcn_rcpf(c1.w);

    // load 8x8 tile into registers (8 independent 16B loads)
    V8 pf[8];
    #pragma unroll
    for (int i = 0; i < 8; ++i)
        pf[i] = loadP8(P + (size_t)(row0 + i) * N, col0);

    // row partials -> wave reduce -> LDS
    #pragma unroll
    for (int i = 0; i < 8; ++i) {
        float s = pf[i].v[0] * v[0] + pf[i].v[1] * v[1] + pf[i].v[2] * v[2] + pf[i].v[3] * v[3]
                + pf[i].v[4] * v[4] + pf[i].v[5] * v[5] + pf[i].v[6] * v[6] + pf[i].v[7] * v[7];
        #pragma unroll
        for (int off = 32; off; off >>= 1) s += __shfl_xor(s, off, 64);
        if (lane == 0) ldsRow[i][wv] = s;
    }
    __syncthreads();

    // combine 8 wave-partials per row; u = rcp(rowsum); publish
    if (t < 64) {
        const int row = t >> 3, w = t & 7;
        float s = ldsRow[row][w];
        s += __shfl_xor(s, 1, 64);
        s += __shfl_xor(s, 2, 64);
        s += __shfl_xor(s, 4, 64);
        if (w == 0) {
            float u = __builtin_amdgcn_rcpf(s);
            ldsU[row] = u;
            u_glob[row0 + row] = u;      // persisted for k_final (last iter wins)
        }
    }
    __syncthreads();

    // col contribution: acc_k = sum_i u_i * P_ik  (cols private to this thread)
    float acc[8] = {0, 0, 0, 0, 0, 0, 0, 0};
    #pragma unroll
    for (int i = 0; i < 8; ++i) {
        const float u = ldsU[i];
        #pragma unroll
        for (int k = 0; k < 8; ++k) acc[k] += u * pf[i].v[k];
    }
    #pragma unroll
    for (int k = 0; k < 8; ++k) atomicAdd(&csum_cur[col0 + k], acc[k]);

    // reset the stale third buffer (read by everyone last dispatch; next cur)
    if (t < 8) csum_reset[b * 8 + t] = 0.0f;
}

// --------------------------------------------------------------- final ------
// out[i][j] = u_i * P[i][j] * rcp(csum_last[j]).  f32 path: P==out, in-place OK
// (each element read and written by the same thread).
template<typename PT>
__global__ __launch_bounds__(256) void k_final(const PT* __restrict__ P,
                                               const float* __restrict__ u_glob,
                                               const float* __restrict__ csum_last,
                                               float* __restrict__ out) {
    const int idx = blockIdx.x * 256 + threadIdx.x;        // 0 .. N*N/8-1
    const int row = idx >> 9;
    const int c8  = (idx & 511) * 8;
    const float u = u_glob[row];
    float4 cc0 = *(const float4*)&csum_last[c8];
    float4 cc1 = *(const float4*)&csum_last[c8 + 4];
    V8 p = loadP8(P + (size_t)row * N, c8);
    float4 a, bq;
    a.x  = p.v[0] * u * __builtin_amdgcn_rcpf(cc0.x);
    a.y  = p.v[1] * u * __builtin_amdgcn_rcpf(cc0.y);
    a.z  = p.v[2] * u * __builtin_amdgcn_rcpf(cc0.z);
    a.w  = p.v[3] * u * __builtin_amdgcn_rcpf(cc0.w);
    bq.x = p.v[4] * u * __builtin_amdgcn_rcpf(cc1.x);
    bq.y = p.v[5] * u * __builtin_amdgcn_rcpf(cc1.y);
    bq.z = p.v[6] * u * __builtin_amdgcn_rcpf(cc1.z);
    bq.w = p.v[7] * u * __builtin_amdgcn_rcpf(cc1.w);
    float4* o4 = (float4*)out;
    o4[2 * (size_t)idx]     = a;
    o4[2 * (size_t)idx + 1] = bq;
}

// ------------------------------------------------------------- launcher -----
extern "C" void kernel_launch(void* const* d_in, const int* in_sizes, int n_in,
                              void* d_out, int out_size, void* d_ws, size_t ws_size,
                              hipStream_t stream) {
    const float* eps  = (const float*)d_in[0];
    const float* mean = (const float*)d_in[1];
    const float* stdv = (const float*)d_in[2];
    float* out = (float*)d_out;
    char* ws = (char*)d_ws;

    float* vecs = (float*)ws;                 // buf0,buf1,buf2,u  (4 x 16 KB)
    float* buf[3] = { vecs, vecs + N, vecs + 2 * N };
    float* u_glob = vecs + 3 * N;
    const size_t pOff   = 64 * 1024;
    const size_t pBytes = (size_t)N * N * sizeof(unsigned short);

    const int initGrid  = N * N / 8 / 512;    // 4096
    const int finalGrid = N * N / 8 / 256;    // 8192

    if (ws_size >= pOff + pBytes) {
        unsigned short* P = (unsigned short*)(ws + pOff);
        k_init<unsigned short><<<initGrid, 512, 0, stream>>>(eps, mean, stdv, P, buf[0], buf[1]);
        for (int t = 1; t <= IT; ++t)
            k_iter<unsigned short><<<NBLK, TPB, 0, stream>>>(
                P, buf[(t - 1) % 3], buf[t % 3], buf[(t + 1) % 3], u_glob);
        k_final<unsigned short><<<finalGrid, 256, 0, stream>>>(P, u_glob, buf[IT % 3], out);
    } else {
        float* P = out;                       // f32 fallback lives in d_out
        k_init<float><<<initGrid, 512, 0, stream>>>(eps, mean, stdv, P, buf[0], buf[1]);
        for (int t = 1; t <= IT; ++t)
            k_iter<float><<<NBLK, TPB, 0, stream>>>(
                P, buf[(t - 1) % 3], buf[t % 3], buf[(t + 1) % 3], u_glob);
        k_final<float><<<finalGrid, 256, 0, stream>>>(P, u_glob, buf[IT % 3], out);
    }
}

// Round 5
// 647.539 us; speedup vs baseline: 7.7424x; 7.7424x over previous
//
#include <hip/hip_runtime.h>

// Sinkhorn-Knopp, linear domain. One pass over P per iteration, NO atomics.
//   P = exp((mean+std*eps)/TAU) bf16 (f32-in-d_out fallback).
//   k_iter  (512 blk x 512 thr, 8 rows/blk, thread owns 8 cols):
//       v_j = rcp(csum_prev[j]);  u_i = rcp(sum_j P_ij v_j)  [block-local]
//       partial[b][j] = sum_{i in blk} u_i P_ij   -> coalesced 16 KB store
//   k_reduce (64 blk x 512 thr): csum_cur[j] = sum_b partial[b][j]
//   Sync = kernel launch boundary (R3: hand-rolled grid barrier ~70us - avoid;
//   R4: contended atomicAdd = 330ns/op/addr + 32B HBM write each - avoid).

constexpr int N    = 4096;
constexpr int IT   = 30;
constexpr int NBLK = 512;           // iter blocks; 8 rows each
constexpr int TPB  = 512;

typedef __attribute__((ext_vector_type(8))) unsigned short ushort8v;

__device__ inline float bf2f(unsigned int h) {
    union { unsigned int u; float f; } x; x.u = h << 16; return x.f;
}
__device__ inline unsigned short f2bf(float f) {
    union { float f; unsigned int u; } x; x.f = f;
    unsigned int r = x.u + 0x7FFFu + ((x.u >> 16) & 1u);   // round-nearest-even
    return (unsigned short)(r >> 16);
}

struct V8 { float v[8]; };

template<typename PT>
__device__ inline V8 loadP8(const PT* base, int e);
template<> __device__ inline V8 loadP8<unsigned short>(const unsigned short* base, int e) {
    ushort8v p = *(const ushort8v*)(base + e);             // one dwordx4
    V8 r;
    #pragma unroll
    for (int k = 0; k < 8; ++k) r.v[k] = bf2f((unsigned int)p[k]);
    return r;
}
template<> __device__ inline V8 loadP8<float>(const float* base, int e) {
    float4 a = *(const float4*)(base + e);
    float4 b = *(const float4*)(base + e + 4);
    V8 r = {{a.x, a.y, a.z, a.w, b.x, b.y, b.z, b.w}};
    return r;
}

// ---------------------------------------------------------------- init ------
template<typename PT>
__global__ __launch_bounds__(512) void k_init(const float* __restrict__ eps,
                                              const float* __restrict__ mean,
                                              const float* __restrict__ stdv,
                                              PT* __restrict__ P,
                                              float* __restrict__ bufA) {
    const int idx = blockIdx.x * 512 + threadIdx.x;        // 0 .. N*N/8-1
    const float4* e4 = (const float4*)eps;
    const float4* m4 = (const float4*)mean;
    const float4* s4 = (const float4*)stdv;
    float4 e0 = e4[2 * (size_t)idx], e1 = e4[2 * (size_t)idx + 1];
    float4 m0 = m4[2 * (size_t)idx], m1 = m4[2 * (size_t)idx + 1];
    float4 s0 = s4[2 * (size_t)idx], s1 = s4[2 * (size_t)idx + 1];
    float p[8];
    p[0] = __expf((m0.x + s0.x * e0.x) * 0.5f);
    p[1] = __expf((m0.y + s0.y * e0.y) * 0.5f);
    p[2] = __expf((m0.z + s0.z * e0.z) * 0.5f);
    p[3] = __expf((m0.w + s0.w * e0.w) * 0.5f);
    p[4] = __expf((m1.x + s1.x * e1.x) * 0.5f);
    p[5] = __expf((m1.y + s1.y * e1.y) * 0.5f);
    p[6] = __expf((m1.z + s1.z * e1.z) * 0.5f);
    p[7] = __expf((m1.w + s1.w * e1.w) * 0.5f);
    if constexpr (sizeof(PT) == 2) {
        ushort8v o;
        #pragma unroll
        for (int k = 0; k < 8; ++k) o[k] = f2bf(p[k]);
        *(ushort8v*)((unsigned short*)P + 8 * (size_t)idx) = o;
    } else {
        float4* o4 = (float4*)P;
        float4 a = {p[0], p[1], p[2], p[3]}, b = {p[4], p[5], p[6], p[7]};
        o4[2 * (size_t)idx]     = a;
        o4[2 * (size_t)idx + 1] = b;
    }
    if (idx < N) bufA[idx] = 1.0f;     // csum_prev for iter 1: v = rcp(1) = 1
}

// ------------------------------------------------------- fused iteration ----
// Block b: rows [8b,8b+8). Thread t: cols [8t,8t+8). One pass over the tile.
template<typename PT>
__global__ __launch_bounds__(TPB) void k_iter(const PT* __restrict__ P,
                                              const float* __restrict__ csum_prev,
                                              float* __restrict__ partial,
                                              float* __restrict__ u_glob) {
    __shared__ float ldsRow[8][8];   // [row][wave]
    __shared__ float ldsU[8];
    const int t    = threadIdx.x;
    const int wv   = t >> 6, lane = t & 63;
    const int b    = blockIdx.x;
    const int col0 = t * 8;
    const int row0 = b * 8;

    float4 c0 = *(const float4*)&csum_prev[col0];
    float4 c1 = *(const float4*)&csum_prev[col0 + 4];
    float v[8];
    v[0] = __builtin_amdgcn_rcpf(c0.x);  v[1] = __builtin_amdgcn_rcpf(c0.y);
    v[2] = __builtin_amdgcn_rcpf(c0.z);  v[3] = __builtin_amdgcn_rcpf(c0.w);
    v[4] = __builtin_amdgcn_rcpf(c1.x);  v[5] = __builtin_amdgcn_rcpf(c1.y);
    v[6] = __builtin_amdgcn_rcpf(c1.z);  v[7] = __builtin_amdgcn_rcpf(c1.w);

    V8 pf[8];
    #pragma unroll
    for (int i = 0; i < 8; ++i)
        pf[i] = loadP8(P + (size_t)(row0 + i) * N, col0);

    // row partials -> wave reduce -> LDS
    #pragma unroll
    for (int i = 0; i < 8; ++i) {
        float s = pf[i].v[0] * v[0] + pf[i].v[1] * v[1] + pf[i].v[2] * v[2] + pf[i].v[3] * v[3]
                + pf[i].v[4] * v[4] + pf[i].v[5] * v[5] + pf[i].v[6] * v[6] + pf[i].v[7] * v[7];
        #pragma unroll
        for (int off = 32; off; off >>= 1) s += __shfl_xor(s, off, 64);
        if (lane == 0) ldsRow[i][wv] = s;
    }
    __syncthreads();

    if (t < 64) {
        const int row = t >> 3, w = t & 7;
        float s = ldsRow[row][w];
        s += __shfl_xor(s, 1, 64);
        s += __shfl_xor(s, 2, 64);
        s += __shfl_xor(s, 4, 64);
        if (w == 0) {
            float u = __builtin_amdgcn_rcpf(s);
            ldsU[row] = u;
            u_glob[row0 + row] = u;          // last iteration's value used by k_final
        }
    }
    __syncthreads();

    // col contribution for this block's 8 rows; single-writer coalesced store
    float acc[8] = {0, 0, 0, 0, 0, 0, 0, 0};
    #pragma unroll
    for (int i = 0; i < 8; ++i) {
        const float u = ldsU[i];
        #pragma unroll
        for (int k = 0; k < 8; ++k) acc[k] += u * pf[i].v[k];
    }
    float4* dst = (float4*)&partial[(size_t)b * N + col0];
    float4 a = {acc[0], acc[1], acc[2], acc[3]};
    float4 bb = {acc[4], acc[5], acc[6], acc[7]};
    dst[0] = a;
    dst[1] = bb;
}

// ----------------------------------------------------------- col reduce -----
// 64 blocks x 512 thr. Block owns 64 cols; wave w sums partial chunk w.
__global__ __launch_bounds__(512) void k_reduce(const float* __restrict__ partial,
                                                float* __restrict__ csum_cur) {
    __shared__ float red[8][64];
    const int t = threadIdx.x;
    const int lane = t & 63, wv = t >> 6;          // wv = chunk 0..7
    const int col = blockIdx.x * 64 + lane;
    float s = 0.0f;
    const float* p = partial + (size_t)(wv * 64) * N + col;
    #pragma unroll 8
    for (int b = 0; b < 64; ++b)
        s += p[(size_t)b * N];
    red[wv][lane] = s;
    __syncthreads();
    if (t < 64) {
        float acc = 0.0f;
        #pragma unroll
        for (int w = 0; w < 8; ++w) acc += red[w][t];
        csum_cur[blockIdx.x * 64 + t] = acc;
    }
}

// --------------------------------------------------------------- final ------
template<typename PT>
__global__ __launch_bounds__(256) void k_final(const PT* __restrict__ P,
                                               const float* __restrict__ u_glob,
                                               const float* __restrict__ csum_last,
                                               float* __restrict__ out) {
    const int idx = blockIdx.x * 256 + threadIdx.x;        // 0 .. N*N/8-1
    const int row = idx >> 9;
    const int c8  = (idx & 511) * 8;
    const float u = u_glob[row];
    float4 cc0 = *(const float4*)&csum_last[c8];
    float4 cc1 = *(const float4*)&csum_last[c8 + 4];
    V8 p = loadP8(P + (size_t)row * N, c8);
    float4 a, bq;
    a.x  = p.v[0] * u * __builtin_amdgcn_rcpf(cc0.x);
    a.y  = p.v[1] * u * __builtin_amdgcn_rcpf(cc0.y);
    a.z  = p.v[2] * u * __builtin_amdgcn_rcpf(cc0.z);
    a.w  = p.v[3] * u * __builtin_amdgcn_rcpf(cc0.w);
    bq.x = p.v[4] * u * __builtin_amdgcn_rcpf(cc1.x);
    bq.y = p.v[5] * u * __builtin_amdgcn_rcpf(cc1.y);
    bq.z = p.v[6] * u * __builtin_amdgcn_rcpf(cc1.z);
    bq.w = p.v[7] * u * __builtin_amdgcn_rcpf(cc1.w);
    float4* o4 = (float4*)out;
    o4[2 * (size_t)idx]     = a;
    o4[2 * (size_t)idx + 1] = bq;
}

// ------------------------------------------------------------- launcher -----
extern "C" void kernel_launch(void* const* d_in, const int* in_sizes, int n_in,
                              void* d_out, int out_size, void* d_ws, size_t ws_size,
                              hipStream_t stream) {
    const float* eps  = (const float*)d_in[0];
    const float* mean = (const float*)d_in[1];
    const float* stdv = (const float*)d_in[2];
    float* out = (float*)d_out;
    char* ws = (char*)d_ws;

    // ws layout: [bufA bufB u_glob (64KB)] [partial 8MiB] [P bf16 32MiB]
    float* bufA   = (float*)ws;
    float* bufB   = bufA + N;
    float* u_glob = bufB + N;
    const size_t partOff = 64 * 1024;
    float* partial = (float*)(ws + partOff);
    const size_t partBytes = (size_t)NBLK * N * sizeof(float);     // 8 MiB
    const size_t pOff   = partOff + partBytes;
    const size_t pBytes = (size_t)N * N * sizeof(unsigned short);  // 32 MiB

    const int initGrid  = N * N / 8 / 512;    // 4096
    const int finalGrid = N * N / 8 / 256;    // 8192

    float* cs[2] = { bufA, bufB };

    if (ws_size >= pOff + pBytes) {
        unsigned short* P = (unsigned short*)(ws + pOff);
        k_init<unsigned short><<<initGrid, 512, 0, stream>>>(eps, mean, stdv, P, bufA);
        for (int t = 1; t <= IT; ++t) {
            k_iter<unsigned short><<<NBLK, TPB, 0, stream>>>(P, cs[(t - 1) & 1], partial, u_glob);
            k_reduce<<<64, 512, 0, stream>>>(partial, cs[t & 1]);
        }
        k_final<unsigned short><<<finalGrid, 256, 0, stream>>>(P, u_glob, cs[IT & 1], out);
    } else {
        float* P = out;                       // f32 fallback: P lives in d_out
        k_init<float><<<initGrid, 512, 0, stream>>>(eps, mean, stdv, P, bufA);
        for (int t = 1; t <= IT; ++t) {
            k_iter<float><<<NBLK, TPB, 0, stream>>>(P, cs[(t - 1) & 1], partial, u_glob);
            k_reduce<<<64, 512, 0, stream>>>(partial, cs[t & 1]);
        }
        k_final<float><<<finalGrid, 256, 0, stream>>>(P, u_glob, cs[IT & 1], out);
    }
}